// Round 13
// baseline (135.021 us; speedup 1.0000x reference)
//
#include <hip/hip_runtime.h>
#include <hip/hip_bf16.h>
#include <cmath>

// Problem constants
#define B_  16
#define N_  512
#define H_  8
#define F0_ 64
#define DEMB_ 64
#define FIN0_ 131   // 64 + 64 + 3
#define KP0_ 192    // padded K for layer-0 GEMM
#define O_  128
#define FIN1_ 1024  // H_*O_
#define LOG2E_ 1.4426950408889634f

typedef __attribute__((ext_vector_type(4))) float f32x4;
typedef __attribute__((ext_vector_type(8))) short bf16x8;

__device__ inline ushort f2bf(float f) {
    union { float f; unsigned u; } x; x.f = f;
    unsigned r = x.u + 0x7fff + ((x.u >> 16) & 1);   // RNE
    return (ushort)(r >> 16);
}
__device__ inline float bf2f(ushort u) {
    union { unsigned u; float f; } x; x.u = ((unsigned)u) << 16;
    return x.f;
}
__device__ inline float tanh_fast(float x) {
    x = fminf(fmaxf(x, -15.f), 15.f);
    float e = __expf(2.f * x);
    return (e - 1.f) * __frcp_rn(e + 1.f);
}

// ---------------------------------------------------------------------------
// Merged preprocessing: one kernel, block-range dispatch.
//  [0,2048):      copy h -> x0p cols 0..63; zero cols 131..191
//  [2048,3072):   emb instance-norm -> x0p cols 64..127
//  [3072,3120):   ue instance-norm  -> x0p cols 128..130
//  [3120,3728):   weight transpose/convert
//  [3728,20112):  adj>0 bitmask
// ---------------------------------------------------------------------------
__global__ __launch_bounds__(256) void k_pre(const float* __restrict__ h,
                                             const int* __restrict__ verts,
                                             const float* __restrict__ table,
                                             const float* __restrict__ n1w,
                                             const float* __restrict__ n1b,
                                             const float* __restrict__ ue,
                                             const float* __restrict__ n2w,
                                             const float* __restrict__ n2b,
                                             const float* __restrict__ w0,
                                             const float* __restrict__ w1,
                                             const float* __restrict__ adj,
                                             ushort* __restrict__ x0,
                                             ushort* __restrict__ wt0,
                                             ushort* __restrict__ wt1,
                                             unsigned long long* __restrict__ mask) {
    __shared__ float s0[256], s1[256];
    int bid = blockIdx.x;
    int t = threadIdx.x;

    if (bid < 2048) {
        int i = bid * 256 + t;
        int r = i >> 6, c = i & 63;
        x0[(size_t)r * KP0_ + c] = f2bf(h[i]);
        if (c >= 3) x0[(size_t)r * KP0_ + 128 + c] = 0;
    } else if (bid < 3072) {
        int b2 = bid - 2048;
        int b = b2 >> 6, c = b2 & 63;
        float vals[2], sum = 0.f, sq = 0.f;
#pragma unroll
        for (int i = 0; i < 2; ++i) {
            int n = t + i * 256;
            int vid = verts[b * N_ + n];
            float v = table[(size_t)vid * DEMB_ + c];
            vals[i] = v; sum += v; sq += v * v;
        }
        s0[t] = sum; s1[t] = sq; __syncthreads();
        for (int o = 128; o > 0; o >>= 1) {
            if (t < o) { s0[t] += s0[t + o]; s1[t] += s1[t + o]; }
            __syncthreads();
        }
        float mu = s0[0] * (1.f / N_);
        float var = s1[0] * (1.f / N_) - mu * mu;
        float inv = rsqrtf(var + 1e-5f);
        float ww = n1w[c], bv = n1b[c];
#pragma unroll
        for (int i = 0; i < 2; ++i) {
            int n = t + i * 256;
            x0[((size_t)b * N_ + n) * KP0_ + 64 + c] = f2bf((vals[i] - mu) * inv * ww + bv);
        }
    } else if (bid < 3120) {
        int b3 = bid - 3072;
        int b = b3 / 3, c = b3 % 3;
        float vals[2], sum = 0.f, sq = 0.f;
#pragma unroll
        for (int i = 0; i < 2; ++i) {
            int n = t + i * 256;
            float v = ue[((size_t)b * N_ + n) * 3 + c];
            vals[i] = v; sum += v; sq += v * v;
        }
        s0[t] = sum; s1[t] = sq; __syncthreads();
        for (int o = 128; o > 0; o >>= 1) {
            if (t < o) { s0[t] += s0[t + o]; s1[t] += s1[t + o]; }
            __syncthreads();
        }
        float mu = s0[0] * (1.f / N_);
        float var = s1[0] * (1.f / N_) - mu * mu;
        float inv = rsqrtf(var + 1e-5f);
        float ww = n2w[c], bv = n2b[c];
#pragma unroll
        for (int i = 0; i < 2; ++i) {
            int n = t + i * 256;
            x0[((size_t)b * N_ + n) * KP0_ + 128 + c] = f2bf((vals[i] - mu) * inv * ww + bv);
        }
    } else if (bid < 3728) {
        int ob = (bid - 3120) * 2 + (t >> 7);
        int o = t & 127;
        if (ob < 192) {
            int hh = ob / 24, kc = ob % 24;
            bf16x8 v;
#pragma unroll
            for (int j = 0; j < 8; ++j) {
                int k = kc * 8 + j;
                float f = (k < FIN0_) ? w0[((size_t)hh * FIN0_ + k) * 128 + o] : 0.f;
                v[j] = (short)f2bf(f);
            }
            *(bf16x8*)(wt0 + ((size_t)(hh * 128 + o)) * KP0_ + kc * 8) = v;
        } else {
            int b2 = ob - 192;
            int hh = b2 >> 7, kc = b2 & 127;
            bf16x8 v;
#pragma unroll
            for (int j = 0; j < 8; ++j) {
                int k = kc * 8 + j;
                float f = w1[((size_t)hh * FIN1_ + k) * 128 + o];
                v[j] = (short)f2bf(f);
            }
            *(bf16x8*)(wt1 + ((size_t)(hh * 128 + o)) * FIN1_ + kc * 8) = v;
        }
    } else {
        int gid = (bid - 3728) * 256 + t;
        float v = adj[gid];
        unsigned long long m = __ballot(v > 0.f);
        if ((t & 63) == 0) mask[gid >> 6] = m;
    }
}

// ---------------------------------------------------------------------------
// MFMA GEMM + fused s/d (one head per block, 512 blocks, 2/CU).
// XCD mapping: xcd = bid&7 = mt&7 -> per-XCD A working set 2 MB (L2-fits).
// ---------------------------------------------------------------------------
template <int K>
__global__ __launch_bounds__(256, 2) void k_gemm(const ushort* __restrict__ A,
                                                 const ushort* __restrict__ Wt,
                                                 const float* __restrict__ asrc,
                                                 const float* __restrict__ adst,
                                                 ushort* __restrict__ hpT,
                                                 float* __restrict__ sout,
                                                 float* __restrict__ dout) {
    __shared__ ushort As[128 * 64];
    __shared__ ushort Bs[128 * 64];
    int bid = blockIdx.x;
    int idx = bid >> 3;
    int mt = (bid & 7) + 8 * (idx & 7);   // 128-row tile, mt&7 == XCD
    int hh = idx >> 3;                    // head
    int tid = threadIdx.x;
    int wid = tid >> 6, l = tid & 63;
    int wm = wid >> 1, wn = wid & 1;

    const ushort* Ab = A + (size_t)mt * 128 * K;
    const ushort* Wb = Wt + (size_t)hh * 128 * K;

    f32x4 acc[4][4];
#pragma unroll
    for (int m = 0; m < 4; ++m)
#pragma unroll
        for (int n = 0; n < 4; ++n) acc[m][n] = (f32x4){0.f, 0.f, 0.f, 0.f};

    int srow = tid >> 3;
    int segp = tid & 7;

    for (int kt = 0; kt < K / 64; ++kt) {
        int k0 = kt * 64;
#pragma unroll
        for (int it = 0; it < 4; ++it) {
            int row = it * 32 + srow;
            int segl = segp ^ (row & 7);
            size_t goff = (size_t)row * K + k0 + segl * 8;
            int loff = (it * 32 + wid * 8) * 64;
            __builtin_amdgcn_global_load_lds(
                (const __attribute__((address_space(1))) void*)(Ab + goff),
                (__attribute__((address_space(3))) void*)(As + loff), 16, 0, 0);
            __builtin_amdgcn_global_load_lds(
                (const __attribute__((address_space(1))) void*)(Wb + goff),
                (__attribute__((address_space(3))) void*)(Bs + loff), 16, 0, 0);
        }
        __syncthreads();

        int lr = l & 15;
        int kg = l >> 4;
#pragma unroll
        for (int kk = 0; kk < 2; ++kk) {
            int segl = kk * 4 + kg;
            bf16x8 a[4], b[4];
#pragma unroll
            for (int m = 0; m < 4; ++m) {
                int row = wm * 64 + m * 16 + lr;
                int sp = segl ^ (row & 7);
                a[m] = *(const bf16x8*)(As + row * 64 + sp * 8);
            }
#pragma unroll
            for (int n = 0; n < 4; ++n) {
                int row = wn * 64 + n * 16 + lr;
                int sp = segl ^ (row & 7);
                b[n] = *(const bf16x8*)(Bs + row * 64 + sp * 8);
            }
#pragma unroll
            for (int m = 0; m < 4; ++m)
#pragma unroll
                for (int n = 0; n < 4; ++n)
                    acc[m][n] = __builtin_amdgcn_mfma_f32_16x16x32_bf16(a[m], b[n], acc[m][n], 0, 0, 0);
        }
        __syncthreads();
    }

    // epilogue 1: hpT write
    int bb = mt >> 2;
    int n_in_b = (mt & 3) * 128;
    int bh = bb * H_ + hh;
    ushort* Hp = hpT + ((size_t)bh * 128) * 512;
#pragma unroll
    for (int m = 0; m < 4; ++m)
#pragma unroll
        for (int n = 0; n < 4; ++n) {
            int rr = wm * 64 + m * 16 + (l >> 4) * 4;
            int cc = wn * 64 + n * 16 + (l & 15);
            ushort4 v;
            v.x = f2bf(acc[m][n][0]);
            v.y = f2bf(acc[m][n][1]);
            v.z = f2bf(acc[m][n][2]);
            v.w = f2bf(acc[m][n][3]);
            *(ushort4*)(Hp + (size_t)cc * 512 + n_in_b + rr) = v;
        }

    // epilogue 2: fused s/d row-reduce, pre-scaled by log2e
    float* sP = (float*)As;
    float* dP = sP + 256;
    float av[4], dv[4];
#pragma unroll
    for (int n = 0; n < 4; ++n) {
        int cc = wn * 64 + n * 16 + (l & 15);
        av[n] = asrc[hh * 128 + cc];
        dv[n] = adst[hh * 128 + cc];
    }
#pragma unroll
    for (int m = 0; m < 4; ++m)
#pragma unroll
        for (int j = 0; j < 4; ++j) {
            float sv = 0.f, dvv = 0.f;
#pragma unroll
            for (int n = 0; n < 4; ++n) {
                float th = tanh_fast(acc[m][n][j]);
                sv += th * av[n];
                dvv += th * dv[n];
            }
#pragma unroll
            for (int off = 1; off < 16; off <<= 1) {
                sv += __shfl_xor(sv, off);
                dvv += __shfl_xor(dvv, off);
            }
            if ((l & 15) == 0) {
                int rr = wm * 64 + m * 16 + (l >> 4) * 4 + j;
                sP[wn * 128 + rr] = sv;
                dP[wn * 128 + rr] = dvv;
            }
        }
    __syncthreads();
    if (tid < 128) {
        sout[(size_t)bh * 512 + n_in_b + tid] = (sP[tid] + sP[128 + tid]) * LOG2E_;
    } else {
        int r = tid - 128;
        dout[(size_t)bh * 512 + n_in_b + r] = (dP[r] + dP[128 + r]) * LOG2E_;
    }
}

// ---------------------------------------------------------------------------
// Fused masked softmax + PV — P LIVES IN REGISTERS (B-fragment layout).
// B-frag of mfma_16x16x32_bf16: lane l holds col=l&15, k=(l>>4)*8+j.
// Assign softmax so lane computes exactly its fragment:
//   n  = n0 + wid*16 + (l&15)        (each wave owns an n-16 group)
//   m  = chunk*64 + ks*32 + (l>>4)*8 + j
// -> no P LDS, no P barrier; rowsum via shfl_xor(16),(32).
// V [128 o][64 m] double-buffered in LDS, 1 barrier per 64-m chunk.
// grid 1024: xcd=bid&7, bh = xcd + 8*(idx&15), tile = idx>>4 (n-64).
// Per wave: acc[8] (o-128 x n-16), 8 MFMA per 32-m step.
// ---------------------------------------------------------------------------
template <bool L0>
__global__ __launch_bounds__(256, 4) void k_attn(const ushort* __restrict__ hpT,
                                                 const float* __restrict__ sbuf,
                                                 const float* __restrict__ dbuf,
                                                 const unsigned* __restrict__ mask32,
                                                 ushort* __restrict__ out) {
    __shared__ ushort Vbuf[2][128 * 64];  // 32 KB double-buffered
    __shared__ float dsh[512];            // 2 KB

    int bid = blockIdx.x;
    int xcd = bid & 7, idx = bid >> 3;
    int bh = xcd + 8 * (idx & 15);
    int tile = idx >> 4;             // 0..7
    int b = bh >> 3, hh = bh & 7;
    int n0 = tile * 64;
    int t = threadIdx.x;
    int wid = t >> 6, l = t & 63;
    int lr = l & 15, kg = l >> 4;

    const ushort* Vb = hpT + (size_t)bh * 128 * 512;   // [o][node]

    int nn = n0 + wid * 16 + lr;     // this lane's n (column)
    float sv = sbuf[(size_t)bh * 512 + nn];
    unsigned mw[16];
#pragma unroll
    for (int w = 0; w < 16; ++w)
        mw[w] = mask32[((size_t)(b * 512 + nn) << 4) + w];

    int srow = t >> 3, segp = t & 7;

    // prologue: stage V chunk 0 + d
#pragma unroll
    for (int it = 0; it < 4; ++it) {
        int rrow = it * 32 + srow;
        int segl = segp ^ (rrow & 7);
        __builtin_amdgcn_global_load_lds(
            (const __attribute__((address_space(1))) void*)(Vb + (size_t)rrow * 512 + segl * 8),
            (__attribute__((address_space(3))) void*)(Vbuf[0] + (it * 32 + wid * 8) * 64),
            16, 0, 0);
    }
    dsh[t] = dbuf[(size_t)bh * 512 + t];
    dsh[256 + t] = dbuf[(size_t)bh * 512 + 256 + t];

    f32x4 acc[8];
#pragma unroll
    for (int f = 0; f < 8; ++f) acc[f] = (f32x4){0.f, 0.f, 0.f, 0.f};
    float rsum = 0.f;

#pragma unroll
    for (int c = 0; c < 8; ++c) {
        __syncthreads();   // V[c] ready (drains vmcnt); Vbuf[(c+1)&1] free

        // issue next V chunk (drains at NEXT barrier, a full chunk later)
        if (c < 7) {
            int m1 = (c + 1) * 64;
            ushort* Vnxt = Vbuf[(c + 1) & 1];
#pragma unroll
            for (int it = 0; it < 4; ++it) {
                int rrow = it * 32 + srow;
                int segl = segp ^ (rrow & 7);
                __builtin_amdgcn_global_load_lds(
                    (const __attribute__((address_space(1))) void*)(Vb + (size_t)rrow * 512 + m1 + segl * 8),
                    (__attribute__((address_space(3))) void*)(Vnxt + (it * 32 + wid * 8) * 64),
                    16, 0, 0);
            }
        }

        const ushort* Vcur = Vbuf[c & 1];
#pragma unroll
        for (int ks = 0; ks < 2; ++ks) {
            // B-frag (P) in registers: 8 exp2's for (n=nn, m=c*64+ks*32+kg*8+j)
            const float* dp = dsh + c * 64 + ks * 32 + kg * 8;
            f32x4 da = *(const f32x4*)dp;
            f32x4 db2 = *(const f32x4*)(dp + 4);
            unsigned mwc = mw[c * 2 + ks] >> (kg * 8);
            float ev[8];
#pragma unroll
            for (int q = 0; q < 8; ++q) {
                float dm = (q < 4) ? da[q] : db2[q - 4];
                float lg = sv + dm;
                lg = fmaxf(lg, 0.2f * lg);           // leaky_relu(0.2), scale-safe
                float e = ((mwc >> q) & 1) ? exp2f(lg) : 0.f;
                rsum += e;
                ev[q] = e;
            }
            unsigned p01, p23, p45, p67;
            asm("v_cvt_pk_bf16_f32 %0, %1, %2" : "=v"(p01) : "v"(ev[0]), "v"(ev[1]));
            asm("v_cvt_pk_bf16_f32 %0, %1, %2" : "=v"(p23) : "v"(ev[2]), "v"(ev[3]));
            asm("v_cvt_pk_bf16_f32 %0, %1, %2" : "=v"(p45) : "v"(ev[4]), "v"(ev[5]));
            asm("v_cvt_pk_bf16_f32 %0, %1, %2" : "=v"(p67) : "v"(ev[6]), "v"(ev[7]));
            union { uint4 u; bf16x8 h; } pk;
            pk.u = (uint4){p01, p23, p45, p67};

            // A-frags: V[o-frag][this 32-m slice], MFMA into acc
            int s = ks * 4 + kg;
#pragma unroll
            for (int f = 0; f < 8; ++f) {
                int rw = f * 16 + lr;
                int sp = s ^ (rw & 7);
                bf16x8 a = *(const bf16x8*)(Vcur + rw * 64 + sp * 8);
                acc[f] = __builtin_amdgcn_mfma_f32_16x16x32_bf16(a, pk.h, acc[f], 0, 0, 0);
            }
        }
    }

    // rowsum: lanes sharing l&15 (kg = 0..3) hold partial sums
    rsum += __shfl_xor(rsum, 16);
    rsum += __shfl_xor(rsum, 32);
    float ri = __frcp_rn(rsum);

    // epilogue: normalize + (ELU) + ushort4 stores.
    // D layout: col=l&15 (=n, matches nn), row=(l>>4)*4+j (o within frag).
    size_t orow;
    if (L0)
        orow = ((size_t)(b * 512 + nn)) * FIN1_ + hh * 128;
    else
        orow = ((size_t)bh * 512 + nn) * 128;
#pragma unroll
    for (int f = 0; f < 8; ++f) {
        int o0 = f * 16 + kg * 4;
        f32x4 v = acc[f];
        ushort4 w;
        float f0 = v[0] * ri, f1 = v[1] * ri, f2 = v[2] * ri, f3 = v[3] * ri;
        if (L0) {
            f0 = (f0 > 0.f) ? f0 : expm1f(f0);
            f1 = (f1 > 0.f) ? f1 : expm1f(f1);
            f2 = (f2 > 0.f) ? f2 : expm1f(f2);
            f3 = (f3 > 0.f) ? f3 : expm1f(f3);
        }
        w.x = f2bf(f0); w.y = f2bf(f1); w.z = f2bf(f2); w.w = f2bf(f3);
        *(ushort4*)(out + orow + o0) = w;
    }
}

// ---------------------------------------------------------------------------
// mean over heads (bf16 in) + log_softmax over channels(128)
// ---------------------------------------------------------------------------
__global__ __launch_bounds__(128) void k_out(const ushort* __restrict__ o1,
                                             float* __restrict__ out) {
    int row = blockIdx.x;       // b*512+n
    int b = row >> 9, n = row & 511;
    int t = threadIdx.x;
    float v = 0.f;
#pragma unroll
    for (int hh = 0; hh < H_; ++hh)
        v += bf2f(o1[((size_t)(b * H_ + hh) * N_ + n) * O_ + t]);
    v *= 0.125f;
    float m = v;
#pragma unroll
    for (int off = 32; off > 0; off >>= 1) m = fmaxf(m, __shfl_down(m, off));
    __shared__ float red[4];
    if ((t & 63) == 0) red[t >> 6] = m;
    __syncthreads();
    float rm = fmaxf(red[0], red[1]);
    float e = __expf(v - rm);
    float ss = e;
#pragma unroll
    for (int off = 32; off > 0; off >>= 1) ss += __shfl_down(ss, off);
    if ((t & 63) == 0) red[2 + (t >> 6)] = ss;
    __syncthreads();
    float rs2 = red[2] + red[3];
    out[(size_t)row * O_ + t] = v - rm - logf(rs2);
}

// ---------------------------------------------------------------------------
extern "C" void kernel_launch(void* const* d_in, const int* in_sizes, int n_in,
                              void* d_out, int out_size, void* d_ws, size_t ws_size,
                              hipStream_t stream) {
    const int*   verts = (const int*)d_in[0];
    const float* adj   = (const float*)d_in[1];
    const float* h     = (const float*)d_in[2];
    const float* ue    = (const float*)d_in[3];
    const float* table = (const float*)d_in[4];
    const float* n1w   = (const float*)d_in[5];
    const float* n1b   = (const float*)d_in[6];
    const float* n2w   = (const float*)d_in[7];
    const float* n2b   = (const float*)d_in[8];
    const float* w0    = (const float*)d_in[9];
    const float* as0   = (const float*)d_in[10];
    const float* ad0   = (const float*)d_in[11];
    const float* w1    = (const float*)d_in[12];
    const float* as1   = (const float*)d_in[13];
    const float* ad1   = (const float*)d_in[14];
    float* out = (float*)d_out;

    // workspace layout (ushort units)
    ushort* x0p  = (ushort*)d_ws;                 // 1,572,864
    ushort* wt0  = x0p + 1572864;                 // 196,608
    ushort* wt1  = wt0 + 196608;                  // 1,048,576
    ushort* hpT  = wt1 + 1048576;                 // 8,388,608
    ushort* x1bf = hpT + 8388608;                 // 8,388,608
    ushort* o1   = x1bf + 8388608;                // 8,388,608
    unsigned long long* mask = (unsigned long long*)(o1 + 8388608);  // 65,536 words
    float* sb = (float*)(mask + 65536);           // 65,536 f
    float* db = sb + 65536;                       // 65,536 f

    hipLaunchKernelGGL(k_pre, dim3(20112), dim3(256), 0, stream,
                       h, verts, table, n1w, n1b, ue, n2w, n2b, w0, w1, adj,
                       x0p, wt0, wt1, mask);

    // layer 0 (s/d fused into GEMM epilogue)
    hipLaunchKernelGGL((k_gemm<KP0_>), dim3(512), dim3(256), 0, stream,
                       x0p, wt0, as0, ad0, hpT, sb, db);
    hipLaunchKernelGGL((k_attn<true>), dim3(1024), dim3(256), 0, stream,
                       hpT, sb, db, (const unsigned*)mask, x1bf);

    // layer 1
    hipLaunchKernelGGL((k_gemm<FIN1_>), dim3(512), dim3(256), 0, stream,
                       x1bf, wt1, as1, ad1, hpT, sb, db);
    hipLaunchKernelGGL((k_attn<false>), dim3(1024), dim3(256), 0, stream,
                       hpT, sb, db, (const unsigned*)mask, o1);

    // mean over heads + log_softmax
    hipLaunchKernelGGL(k_out, dim3(8192), dim3(128), 0, stream, o1, out);
}

// Round 15
// 116.638 us; speedup vs baseline: 1.1576x; 1.1576x over previous
//
#include <hip/hip_runtime.h>
#include <hip/hip_bf16.h>
#include <cmath>

// Problem constants
#define B_  16
#define N_  512
#define H_  8
#define F0_ 64
#define DEMB_ 64
#define FIN0_ 131   // 64 + 64 + 3
#define KP0_ 192    // padded K for layer-0 GEMM
#define O_  128
#define FIN1_ 1024  // H_*O_
#define LOG2E_ 1.4426950408889634f

typedef __attribute__((ext_vector_type(4))) float f32x4;
typedef __attribute__((ext_vector_type(8))) short bf16x8;

__device__ inline ushort f2bf(float f) {
    union { float f; unsigned u; } x; x.f = f;
    unsigned r = x.u + 0x7fff + ((x.u >> 16) & 1);   // RNE
    return (ushort)(r >> 16);
}
__device__ inline float bf2f(ushort u) {
    union { unsigned u; float f; } x; x.u = ((unsigned)u) << 16;
    return x.f;
}
__device__ inline float tanh_fast(float x) {
    x = fminf(fmaxf(x, -15.f), 15.f);
    float e = __expf(2.f * x);
    return (e - 1.f) * __frcp_rn(e + 1.f);
}

// ---------------------------------------------------------------------------
// Merged preprocessing: one kernel, block-range dispatch.
//  [0,2048):      copy h -> x0p cols 0..63; zero cols 131..191
//  [2048,3072):   emb instance-norm -> x0p cols 64..127
//  [3072,3120):   ue instance-norm  -> x0p cols 128..130
//  [3120,3728):   weight transpose/convert
//  [3728,20112):  adj>0 bitmask
// ---------------------------------------------------------------------------
__global__ __launch_bounds__(256) void k_pre(const float* __restrict__ h,
                                             const int* __restrict__ verts,
                                             const float* __restrict__ table,
                                             const float* __restrict__ n1w,
                                             const float* __restrict__ n1b,
                                             const float* __restrict__ ue,
                                             const float* __restrict__ n2w,
                                             const float* __restrict__ n2b,
                                             const float* __restrict__ w0,
                                             const float* __restrict__ w1,
                                             const float* __restrict__ adj,
                                             ushort* __restrict__ x0,
                                             ushort* __restrict__ wt0,
                                             ushort* __restrict__ wt1,
                                             unsigned long long* __restrict__ mask) {
    __shared__ float s0[256], s1[256];
    int bid = blockIdx.x;
    int t = threadIdx.x;

    if (bid < 2048) {
        int i = bid * 256 + t;
        int r = i >> 6, c = i & 63;
        x0[(size_t)r * KP0_ + c] = f2bf(h[i]);
        if (c >= 3) x0[(size_t)r * KP0_ + 128 + c] = 0;
    } else if (bid < 3072) {
        int b2 = bid - 2048;
        int b = b2 >> 6, c = b2 & 63;
        float vals[2], sum = 0.f, sq = 0.f;
#pragma unroll
        for (int i = 0; i < 2; ++i) {
            int n = t + i * 256;
            int vid = verts[b * N_ + n];
            float v = table[(size_t)vid * DEMB_ + c];
            vals[i] = v; sum += v; sq += v * v;
        }
        s0[t] = sum; s1[t] = sq; __syncthreads();
        for (int o = 128; o > 0; o >>= 1) {
            if (t < o) { s0[t] += s0[t + o]; s1[t] += s1[t + o]; }
            __syncthreads();
        }
        float mu = s0[0] * (1.f / N_);
        float var = s1[0] * (1.f / N_) - mu * mu;
        float inv = rsqrtf(var + 1e-5f);
        float ww = n1w[c], bv = n1b[c];
#pragma unroll
        for (int i = 0; i < 2; ++i) {
            int n = t + i * 256;
            x0[((size_t)b * N_ + n) * KP0_ + 64 + c] = f2bf((vals[i] - mu) * inv * ww + bv);
        }
    } else if (bid < 3120) {
        int b3 = bid - 3072;
        int b = b3 / 3, c = b3 % 3;
        float vals[2], sum = 0.f, sq = 0.f;
#pragma unroll
        for (int i = 0; i < 2; ++i) {
            int n = t + i * 256;
            float v = ue[((size_t)b * N_ + n) * 3 + c];
            vals[i] = v; sum += v; sq += v * v;
        }
        s0[t] = sum; s1[t] = sq; __syncthreads();
        for (int o = 128; o > 0; o >>= 1) {
            if (t < o) { s0[t] += s0[t + o]; s1[t] += s1[t + o]; }
            __syncthreads();
        }
        float mu = s0[0] * (1.f / N_);
        float var = s1[0] * (1.f / N_) - mu * mu;
        float inv = rsqrtf(var + 1e-5f);
        float ww = n2w[c], bv = n2b[c];
#pragma unroll
        for (int i = 0; i < 2; ++i) {
            int n = t + i * 256;
            x0[((size_t)b * N_ + n) * KP0_ + 128 + c] = f2bf((vals[i] - mu) * inv * ww + bv);
        }
    } else if (bid < 3728) {
        int ob = (bid - 3120) * 2 + (t >> 7);
        int o = t & 127;
        if (ob < 192) {
            int hh = ob / 24, kc = ob % 24;
            bf16x8 v;
#pragma unroll
            for (int j = 0; j < 8; ++j) {
                int k = kc * 8 + j;
                float f = (k < FIN0_) ? w0[((size_t)hh * FIN0_ + k) * 128 + o] : 0.f;
                v[j] = (short)f2bf(f);
            }
            *(bf16x8*)(wt0 + ((size_t)(hh * 128 + o)) * KP0_ + kc * 8) = v;
        } else {
            int b2 = ob - 192;
            int hh = b2 >> 7, kc = b2 & 127;
            bf16x8 v;
#pragma unroll
            for (int j = 0; j < 8; ++j) {
                int k = kc * 8 + j;
                float f = w1[((size_t)hh * FIN1_ + k) * 128 + o];
                v[j] = (short)f2bf(f);
            }
            *(bf16x8*)(wt1 + ((size_t)(hh * 128 + o)) * FIN1_ + kc * 8) = v;
        }
    } else {
        int gid = (bid - 3728) * 256 + t;
        float v = adj[gid];
        unsigned long long m = __ballot(v > 0.f);
        if ((t & 63) == 0) mask[gid >> 6] = m;
    }
}

// ---------------------------------------------------------------------------
// MFMA GEMM + fused s/d (one head per block, 512 blocks, 2/CU).
// XCD mapping: xcd = bid&7 = mt&7 -> per-XCD A working set 2 MB (L2-fits).
// ---------------------------------------------------------------------------
template <int K>
__global__ __launch_bounds__(256, 2) void k_gemm(const ushort* __restrict__ A,
                                                 const ushort* __restrict__ Wt,
                                                 const float* __restrict__ asrc,
                                                 const float* __restrict__ adst,
                                                 ushort* __restrict__ hpT,
                                                 float* __restrict__ sout,
                                                 float* __restrict__ dout) {
    __shared__ ushort As[128 * 64];
    __shared__ ushort Bs[128 * 64];
    int bid = blockIdx.x;
    int idx = bid >> 3;
    int mt = (bid & 7) + 8 * (idx & 7);   // 128-row tile, mt&7 == XCD
    int hh = idx >> 3;                    // head
    int tid = threadIdx.x;
    int wid = tid >> 6, l = tid & 63;
    int wm = wid >> 1, wn = wid & 1;

    const ushort* Ab = A + (size_t)mt * 128 * K;
    const ushort* Wb = Wt + (size_t)hh * 128 * K;

    f32x4 acc[4][4];
#pragma unroll
    for (int m = 0; m < 4; ++m)
#pragma unroll
        for (int n = 0; n < 4; ++n) acc[m][n] = (f32x4){0.f, 0.f, 0.f, 0.f};

    int srow = tid >> 3;
    int segp = tid & 7;

    for (int kt = 0; kt < K / 64; ++kt) {
        int k0 = kt * 64;
#pragma unroll
        for (int it = 0; it < 4; ++it) {
            int row = it * 32 + srow;
            int segl = segp ^ (row & 7);
            size_t goff = (size_t)row * K + k0 + segl * 8;
            int loff = (it * 32 + wid * 8) * 64;
            __builtin_amdgcn_global_load_lds(
                (const __attribute__((address_space(1))) void*)(Ab + goff),
                (__attribute__((address_space(3))) void*)(As + loff), 16, 0, 0);
            __builtin_amdgcn_global_load_lds(
                (const __attribute__((address_space(1))) void*)(Wb + goff),
                (__attribute__((address_space(3))) void*)(Bs + loff), 16, 0, 0);
        }
        __syncthreads();

        int lr = l & 15;
        int kg = l >> 4;
#pragma unroll
        for (int kk = 0; kk < 2; ++kk) {
            int segl = kk * 4 + kg;
            bf16x8 a[4], b[4];
#pragma unroll
            for (int m = 0; m < 4; ++m) {
                int row = wm * 64 + m * 16 + lr;
                int sp = segl ^ (row & 7);
                a[m] = *(const bf16x8*)(As + row * 64 + sp * 8);
            }
#pragma unroll
            for (int n = 0; n < 4; ++n) {
                int row = wn * 64 + n * 16 + lr;
                int sp = segl ^ (row & 7);
                b[n] = *(const bf16x8*)(Bs + row * 64 + sp * 8);
            }
#pragma unroll
            for (int m = 0; m < 4; ++m)
#pragma unroll
                for (int n = 0; n < 4; ++n)
                    acc[m][n] = __builtin_amdgcn_mfma_f32_16x16x32_bf16(a[m], b[n], acc[m][n], 0, 0, 0);
        }
        __syncthreads();
    }

    // epilogue 1: hpT write
    int bb = mt >> 2;
    int n_in_b = (mt & 3) * 128;
    int bh = bb * H_ + hh;
    ushort* Hp = hpT + ((size_t)bh * 128) * 512;
#pragma unroll
    for (int m = 0; m < 4; ++m)
#pragma unroll
        for (int n = 0; n < 4; ++n) {
            int rr = wm * 64 + m * 16 + (l >> 4) * 4;
            int cc = wn * 64 + n * 16 + (l & 15);
            ushort4 v;
            v.x = f2bf(acc[m][n][0]);
            v.y = f2bf(acc[m][n][1]);
            v.z = f2bf(acc[m][n][2]);
            v.w = f2bf(acc[m][n][3]);
            *(ushort4*)(Hp + (size_t)cc * 512 + n_in_b + rr) = v;
        }

    // epilogue 2: fused s/d row-reduce, pre-scaled by log2e
    float* sP = (float*)As;
    float* dP = sP + 256;
    float av[4], dv[4];
#pragma unroll
    for (int n = 0; n < 4; ++n) {
        int cc = wn * 64 + n * 16 + (l & 15);
        av[n] = asrc[hh * 128 + cc];
        dv[n] = adst[hh * 128 + cc];
    }
#pragma unroll
    for (int m = 0; m < 4; ++m)
#pragma unroll
        for (int j = 0; j < 4; ++j) {
            float sv = 0.f, dvv = 0.f;
#pragma unroll
            for (int n = 0; n < 4; ++n) {
                float th = tanh_fast(acc[m][n][j]);
                sv += th * av[n];
                dvv += th * dv[n];
            }
#pragma unroll
            for (int off = 1; off < 16; off <<= 1) {
                sv += __shfl_xor(sv, off);
                dvv += __shfl_xor(dvv, off);
            }
            if ((l & 15) == 0) {
                int rr = wm * 64 + m * 16 + (l >> 4) * 4 + j;
                sP[wn * 128 + rr] = sv;
                dP[wn * 128 + rr] = dvv;
            }
        }
    __syncthreads();
    if (tid < 128) {
        sout[(size_t)bh * 512 + n_in_b + tid] = (sP[tid] + sP[128 + tid]) * LOG2E_;
    } else {
        int r = tid - 128;
        dout[(size_t)bh * 512 + n_in_b + r] = (dP[r] + dP[128 + r]) * LOG2E_;
    }
}

// ---------------------------------------------------------------------------
// Fused masked softmax + PV (round-11 structure) + COALESCED STORE EPILOGUE.
// grid 1024: xcd=bid&7, bh = xcd + 8*(idx&15), tile = idx>>4 (n-64 x o-128).
// P in LDS (Abuf), single V buffer, 2 barriers/chunk.
// Output staged in LDS (Vbuf reuse, XOR-swizzled), then 16B/lane coalesced
// stores: tile = 64 rows x 256 B = 16 KB = 4 iterations x (256 thr x 16 B).
// ---------------------------------------------------------------------------
template <bool L0>
__global__ __launch_bounds__(256, 2) void k_attn(const ushort* __restrict__ hpT,
                                                 const float* __restrict__ sbuf,
                                                 const float* __restrict__ dbuf,
                                                 const unsigned* __restrict__ mask32,
                                                 ushort* __restrict__ out) {
    __shared__ ushort Vbuf[128 * 64];   // 16 KB  [o 128][m 64]; reused as Tbuf
    __shared__ ushort Abuf[64 * 64];    // 8 KB   [n 64][m 64]
    __shared__ float dsh[512];
    __shared__ float rsh[64];

    int bid = blockIdx.x;
    int xcd = bid & 7, idx = bid >> 3;
    int bh = xcd + 8 * (idx & 15);
    int tile = idx >> 4;             // 0..7
    int b = bh >> 3, hh = bh & 7;
    int n0 = tile * 64;
    int t = threadIdx.x;
    int wid = t >> 6, l = t & 63;
    int wm = wid >> 1, wn = wid & 1; // wm: o-half (2x64), wn: n-half (2x32)
    int lr = l & 15, kg = l >> 4;

    const ushort* Vb = hpT + (size_t)bh * 128 * 512;   // [o][node]

    // softmax thread map: row = t>>2 (0..63), q4 = t&3 (16 m's per thread/chunk)
    int row = t >> 2, q4 = t & 3;
    float sv = sbuf[(size_t)bh * 512 + n0 + row];
    int msh = (q4 & 1) * 16;
    unsigned mw[8];
#pragma unroll
    for (int c = 0; c < 8; ++c)
        mw[c] = mask32[((size_t)(b * 512 + n0 + row) << 4) + c * 2 + (q4 >> 1)];

    // stage d
    dsh[t] = dbuf[(size_t)bh * 512 + t];
    dsh[256 + t] = dbuf[(size_t)bh * 512 + 256 + t];
    __syncthreads();

    f32x4 acc[4][2];                 // [o-frag][n-frag]
#pragma unroll
    for (int m = 0; m < 4; ++m)
#pragma unroll
        for (int n = 0; n < 2; ++n) acc[m][n] = (f32x4){0.f, 0.f, 0.f, 0.f};

    float rsum = 0.f;
    int srow = t >> 3, segp = t & 7;

#pragma unroll
    for (int c = 0; c < 8; ++c) {
        int m0 = c * 64;
        // stage V chunk (latency covered by softmax below)
#pragma unroll
        for (int it = 0; it < 4; ++it) {
            int rrow = it * 32 + srow;
            int segl = segp ^ (rrow & 7);
            __builtin_amdgcn_global_load_lds(
                (const __attribute__((address_space(1))) void*)(Vb + (size_t)rrow * 512 + m0 + segl * 8),
                (__attribute__((address_space(3))) void*)(Vbuf + (it * 32 + wid * 8) * 64),
                16, 0, 0);
        }

        // softmax: 16 logits -> unnormalized exp2 -> P chunk
        const float* dp = dsh + m0 + q4 * 16;
        unsigned mwc = mw[c] >> msh;
#pragma unroll
        for (int j = 0; j < 2; ++j) {
            f32x4 da = *(const f32x4*)(dp + j * 8);
            f32x4 db2 = *(const f32x4*)(dp + j * 8 + 4);
            float ev[8];
#pragma unroll
            for (int q = 0; q < 8; ++q) {
                float dm = (q < 4) ? da[q] : db2[q - 4];
                float lg = sv + dm;
                lg = fmaxf(lg, 0.2f * lg);           // leaky_relu(0.2), scale-safe
                float e = ((mwc >> (j * 8 + q)) & 1) ? exp2f(lg) : 0.f;
                rsum += e;
                ev[q] = e;
            }
            unsigned p01, p23, p45, p67;
            asm("v_cvt_pk_bf16_f32 %0, %1, %2" : "=v"(p01) : "v"(ev[0]), "v"(ev[1]));
            asm("v_cvt_pk_bf16_f32 %0, %1, %2" : "=v"(p23) : "v"(ev[2]), "v"(ev[3]));
            asm("v_cvt_pk_bf16_f32 %0, %1, %2" : "=v"(p45) : "v"(ev[4]), "v"(ev[5]));
            asm("v_cvt_pk_bf16_f32 %0, %1, %2" : "=v"(p67) : "v"(ev[6]), "v"(ev[7]));
            int s = q4 * 2 + j;                      // slot 0..7
            int phys = s ^ (row & 7);
            uint4 pk4 = {p01, p23, p45, p67};
            *(uint4*)((char*)Abuf + row * 128 + phys * 16) = pk4;
        }
        __syncthreads();

        // MFMA: D[o][n] += V[o][m-chunk] . P[n][m-chunk]
#pragma unroll
        for (int kk = 0; kk < 2; ++kk) {
            int s = kk * 4 + kg;
            bf16x8 a[4], bfr[2];
#pragma unroll
            for (int m = 0; m < 4; ++m) {
                int rw = wm * 64 + m * 16 + lr;
                int sp = s ^ (rw & 7);
                a[m] = *(const bf16x8*)(Vbuf + rw * 64 + sp * 8);
            }
#pragma unroll
            for (int n = 0; n < 2; ++n) {
                int rw = wn * 32 + n * 16 + lr;
                int sp = s ^ (rw & 7);
                bfr[n] = *(const bf16x8*)(Abuf + rw * 64 + sp * 8);
            }
#pragma unroll
            for (int m = 0; m < 4; ++m)
#pragma unroll
                for (int n = 0; n < 2; ++n)
                    acc[m][n] = __builtin_amdgcn_mfma_f32_16x16x32_bf16(a[m], bfr[n], acc[m][n], 0, 0, 0);
        }
        __syncthreads();
    }

    // rowsum: 4 threads per row
    rsum += __shfl_xor(rsum, 1);
    rsum += __shfl_xor(rsum, 2);
    if (q4 == 0) rsh[row] = rsum;
    __syncthreads();

    // ---- epilogue A: normalize + (ELU) -> staged in LDS (Vbuf reuse) ----
    // Tbuf layout: row r (n), 256 B of o; 16B slot s, phys = s ^ (r&7).
    ushort* Tb = Vbuf;
#pragma unroll
    for (int n = 0; n < 2; ++n) {
        int rr = wn * 32 + n * 16 + lr;          // tile row (n)
        float ri = __frcp_rn(rsh[rr]);
#pragma unroll
        for (int m = 0; m < 4; ++m) {
            int o0 = wm * 64 + m * 16 + kg * 4;
            f32x4 v = acc[m][n];
            ushort4 w;
            float f0 = v[0] * ri, f1 = v[1] * ri, f2 = v[2] * ri, f3 = v[3] * ri;
            if (L0) {
                f0 = (f0 > 0.f) ? f0 : expm1f(f0);
                f1 = (f1 > 0.f) ? f1 : expm1f(f1);
                f2 = (f2 > 0.f) ? f2 : expm1f(f2);
                f3 = (f3 > 0.f) ? f3 : expm1f(f3);
            }
            w.x = f2bf(f0); w.y = f2bf(f1); w.z = f2bf(f2); w.w = f2bf(f3);
            int byte = o0 * 2;                    // 0..254
            int s = byte >> 4;                    // slot 0..15
            int phys = s ^ (rr & 7);
            *(ushort4*)((char*)Tb + rr * 256 + phys * 16 + (byte & 15)) = w;
        }
    }
    __syncthreads();

    // ---- epilogue B: coalesced 16B/lane stores (tile = 16 KB = 4 iters) ----
    size_t base;
    int stride = L0 ? FIN1_ : 128;
    if (L0) base = ((size_t)(b * 512 + n0)) * FIN1_ + hh * 128;
    else    base = ((size_t)bh * 512 + n0) * 128;
#pragma unroll
    for (int it2 = 0; it2 < 4; ++it2) {
        int lin = it2 * 4096 + t * 16;
        int r2 = lin >> 8;                        // 0..63
        int s2 = (lin >> 4) & 15;
        uint4 v = *(const uint4*)((const char*)Tb + r2 * 256 + ((s2 ^ (r2 & 7)) << 4));
        *(uint4*)(out + base + (size_t)r2 * stride + s2 * 8) = v;
    }
}

// ---------------------------------------------------------------------------
// mean over heads (bf16 in) + log_softmax over channels(128)
// ---------------------------------------------------------------------------
__global__ __launch_bounds__(128) void k_out(const ushort* __restrict__ o1,
                                             float* __restrict__ out) {
    int row = blockIdx.x;       // b*512+n
    int b = row >> 9, n = row & 511;
    int t = threadIdx.x;
    float v = 0.f;
#pragma unroll
    for (int hh = 0; hh < H_; ++hh)
        v += bf2f(o1[((size_t)(b * H_ + hh) * N_ + n) * O_ + t]);
    v *= 0.125f;
    float m = v;
#pragma unroll
    for (int off = 32; off > 0; off >>= 1) m = fmaxf(m, __shfl_down(m, off));
    __shared__ float red[4];
    if ((t & 63) == 0) red[t >> 6] = m;
    __syncthreads();
    float rm = fmaxf(red[0], red[1]);
    float e = __expf(v - rm);
    float ss = e;
#pragma unroll
    for (int off = 32; off > 0; off >>= 1) ss += __shfl_down(ss, off);
    if ((t & 63) == 0) red[2 + (t >> 6)] = ss;
    __syncthreads();
    float rs2 = red[2] + red[3];
    out[(size_t)row * O_ + t] = v - rm - logf(rs2);
}

// ---------------------------------------------------------------------------
extern "C" void kernel_launch(void* const* d_in, const int* in_sizes, int n_in,
                              void* d_out, int out_size, void* d_ws, size_t ws_size,
                              hipStream_t stream) {
    const int*   verts = (const int*)d_in[0];
    const float* adj   = (const float*)d_in[1];
    const float* h     = (const float*)d_in[2];
    const float* ue    = (const float*)d_in[3];
    const float* table = (const float*)d_in[4];
    const float* n1w   = (const float*)d_in[5];
    const float* n1b   = (const float*)d_in[6];
    const float* n2w   = (const float*)d_in[7];
    const float* n2b   = (const float*)d_in[8];
    const float* w0    = (const float*)d_in[9];
    const float* as0   = (const float*)d_in[10];
    const float* ad0   = (const float*)d_in[11];
    const float* w1    = (const float*)d_in[12];
    const float* as1   = (const float*)d_in[13];
    const float* ad1   = (const float*)d_in[14];
    float* out = (float*)d_out;

    // workspace layout (ushort units)
    ushort* x0p  = (ushort*)d_ws;                 // 1,572,864
    ushort* wt0  = x0p + 1572864;                 // 196,608
    ushort* wt1  = wt0 + 196608;                  // 1,048,576
    ushort* hpT  = wt1 + 1048576;                 // 8,388,608
    ushort* x1bf = hpT + 8388608;                 // 8,388,608
    ushort* o1   = x1bf + 8388608;                // 8,388,608
    unsigned long long* mask = (unsigned long long*)(o1 + 8388608);  // 65,536 words
    float* sb = (float*)(mask + 65536);           // 65,536 f
    float* db = sb + 65536;                       // 65,536 f

    hipLaunchKernelGGL(k_pre, dim3(20112), dim3(256), 0, stream,
                       h, verts, table, n1w, n1b, ue, n2w, n2b, w0, w1, adj,
                       x0p, wt0, wt1, mask);

    // layer 0 (s/d fused into GEMM epilogue)
    hipLaunchKernelGGL((k_gemm<KP0_>), dim3(512), dim3(256), 0, stream,
                       x0p, wt0, as0, ad0, hpT, sb, db);
    hipLaunchKernelGGL((k_attn<true>), dim3(1024), dim3(256), 0, stream,
                       hpT, sb, db, (const unsigned*)mask, x1bf);

    // layer 1
    hipLaunchKernelGGL((k_gemm<FIN1_>), dim3(512), dim3(256), 0, stream,
                       x1bf, wt1, as1, ad1, hpT, sb, db);
    hipLaunchKernelGGL((k_attn<false>), dim3(1024), dim3(256), 0, stream,
                       hpT, sb, db, (const unsigned*)mask, o1);

    // mean over heads + log_softmax
    hipLaunchKernelGGL(k_out, dim3(8192), dim3(128), 0, stream, o1, out);
}